// Round 1
// baseline (173.465 us; speedup 1.0000x reference)
//
#include <hip/hip_runtime.h>
#include <cstdint>

#define KDIM 128
#define NEIG 64
#define BATCH 131072
#define DT 0.01f

#define MTILE 64
#define LDX 136   // padded bf16 LDS stride (+8 keeps 16B alignment, breaks bank aliasing)
#define LDH 130   // padded fp32 LDS stride (even -> float2-aligned)

typedef __attribute__((ext_vector_type(8))) short short8x;   // 8 bf16 = 4 VGPRs (MFMA A/B frag)
typedef __attribute__((ext_vector_type(4))) float float4x;   // MFMA C/D frag

__device__ __forceinline__ unsigned short f2bf(float f) {
    // round-to-nearest-even fp32 -> bf16 (inputs are finite; no NaN handling needed)
    unsigned int u = __float_as_uint(f);
    u += 0x7FFFu + ((u >> 16) & 1u);
    return (unsigned short)(u >> 16);
}

__device__ __forceinline__ float tanh_fast(float v) {
    float ax = fabsf(v);
    float e  = __expf(-2.0f * ax);              // v_exp_f32
    float r  = __fdividef(1.0f - e, 1.0f + e);  // fast divide, ~1e-6 rel err
    return copysignf(r, v);
}

// Transpose + downconvert weights once per launch: W[k][n] fp32 -> Wt[n][k] bf16.
__global__ void prep_weights(const float* __restrict__ W1, const float* __restrict__ W2,
                             unsigned short* __restrict__ W1t, unsigned short* __restrict__ W2t) {
    int idx = blockIdx.x * 256 + threadIdx.x;   // 0..16383, coalesced read
    int n = idx & 127, k = idx >> 7;
    W1t[n * 128 + k] = f2bf(W1[idx]);
    W2t[n * 128 + k] = f2bf(W2[idx]);
}

__global__ __launch_bounds__(256) void koopman_main(
        const float* __restrict__ x, const float* __restrict__ b1,
        const float* __restrict__ b2, const unsigned short* __restrict__ W1t,
        const unsigned short* __restrict__ W2t, float* __restrict__ y) {
    // Union: stage-1 (Xbf 17408B + Hbf 17408B) vs stage-2 (Hf 33280B) -> 34816 B
    __shared__ __align__(16) char smem[2 * MTILE * LDX * 2];
    unsigned short* Xbf = (unsigned short*)smem;                 // [MTILE][LDX] bf16
    unsigned short* Hbf = (unsigned short*)smem + MTILE * LDX;   // [MTILE][LDX] bf16
    float*          Hf  = (float*)smem;                          // [MTILE][LDH] fp32 (aliases)

    const int tid  = threadIdx.x;
    const int lane = tid & 63;
    const int wave = tid >> 6;
    const int l15  = lane & 15;
    const int quad = lane >> 4;
    const int m_w  = wave * 16;                 // wave-private 16-row tile
    const int rowbase = blockIdx.x * MTILE;

    // ---- stage X tile: fp32 global -> bf16 LDS (float4 coalesced) ----
    const float4* xg4 = (const float4*)(x + (size_t)rowbase * KDIM);
    #pragma unroll
    for (int i = 0; i < 8; ++i) {
        int f = i * 256 + tid;                  // float4 index, 0..2047
        float4 v = xg4[f];
        int e = f * 4, row = e >> 7, col = e & 127;
        ushort4 bq = make_ushort4(f2bf(v.x), f2bf(v.y), f2bf(v.z), f2bf(v.w));
        *(ushort4*)&Xbf[row * LDX + col] = bq;
    }
    __syncthreads();

    // ---- matmul 1: H1 = Xbf @ W1 (per-wave 16 rows x 128 cols) ----
    float4x acc[8];
    #pragma unroll
    for (int nt = 0; nt < 8; ++nt) acc[nt] = (float4x){0.f, 0.f, 0.f, 0.f};
    #pragma unroll
    for (int ks = 0; ks < 4; ++ks) {
        short8x a = *(const short8x*)&Xbf[(m_w + l15) * LDX + ks * 32 + quad * 8];
        #pragma unroll
        for (int nt = 0; nt < 8; ++nt) {
            short8x bfr = *(const short8x*)&W1t[(nt * 16 + l15) * 128 + ks * 32 + quad * 8];
            acc[nt] = __builtin_amdgcn_mfma_f32_16x16x32_bf16(a, bfr, acc[nt], 0, 0, 0);
        }
    }
    // bias + tanh -> Hbf (wave-private rows; barrier only for safety/uniformity)
    #pragma unroll
    for (int nt = 0; nt < 8; ++nt) {
        int col = nt * 16 + l15;
        float bb = b1[col];
        #pragma unroll
        for (int r = 0; r < 4; ++r) {
            float t = tanh_fast(acc[nt][r] + bb);
            Hbf[(m_w + quad * 4 + r) * LDX + col] = f2bf(t);
        }
    }
    __syncthreads();

    // ---- matmul 2: H2 = Hbf @ W2 ----
    float4x acc2[8];
    #pragma unroll
    for (int nt = 0; nt < 8; ++nt) acc2[nt] = (float4x){0.f, 0.f, 0.f, 0.f};
    #pragma unroll
    for (int ks = 0; ks < 4; ++ks) {
        short8x a = *(const short8x*)&Hbf[(m_w + l15) * LDX + ks * 32 + quad * 8];
        #pragma unroll
        for (int nt = 0; nt < 8; ++nt) {
            short8x bfr = *(const short8x*)&W2t[(nt * 16 + l15) * 128 + ks * 32 + quad * 8];
            acc2[nt] = __builtin_amdgcn_mfma_f32_16x16x32_bf16(a, bfr, acc2[nt], 0, 0, 0);
        }
    }
    __syncthreads();   // all Hbf/Xbf reads done before Hf (aliased) writes

    // ---- H2 + b2 -> Hf fp32 ----
    #pragma unroll
    for (int nt = 0; nt < 8; ++nt) {
        int col = nt * 16 + l15;
        float bb = b2[col];
        #pragma unroll
        for (int r = 0; r < 4; ++r) {
            Hf[(m_w + quad * 4 + r) * LDH + col] = acc2[nt][r] + bb;
        }
    }
    __syncthreads();

    // ---- epilogue: block-diag 2x2 rotation-scaling on fp32 x ----
    const float2* xg2 = (const float2*)(x + (size_t)rowbase * KDIM);
    float2*       yg2 = (float2*)(y + (size_t)rowbase * KDIM);
    #pragma unroll
    for (int i = 0; i < 16; ++i) {
        int p = i * 256 + tid;                  // pair index, 0..4095; p = row*64 + j
        int row = p >> 6, j = p & 63;
        float mu = Hf[row * LDH + 2 * j];
        float om = Hf[row * LDH + 2 * j + 1];
        float2 xv = xg2[p];
        float ex = __expf(DT * mu);
        float s, c;
        __sincosf(DT * om, &s, &c);
        float2 yv;
        yv.x = ex * (c * xv.x - s * xv.y);
        yv.y = ex * (s * xv.x + c * xv.y);
        yg2[p] = yv;
    }
}

extern "C" void kernel_launch(void* const* d_in, const int* in_sizes, int n_in,
                              void* d_out, int out_size, void* d_ws, size_t ws_size,
                              hipStream_t stream) {
    const float* x  = (const float*)d_in[0];
    const float* W1 = (const float*)d_in[1];
    const float* b1 = (const float*)d_in[2];
    const float* W2 = (const float*)d_in[3];
    const float* b2 = (const float*)d_in[4];
    float* y = (float*)d_out;

    unsigned short* W1t = (unsigned short*)d_ws;          // 32 KiB
    unsigned short* W2t = W1t + 128 * 128;                // 32 KiB

    prep_weights<<<64, 256, 0, stream>>>(W1, W2, W1t, W2t);
    koopman_main<<<BATCH / MTILE, 256, 0, stream>>>(x, b1, b2, W1t, W2t, y);
}